// Round 10
// baseline (527.707 us; speedup 1.0000x reference)
//
#include <hip/hip_runtime.h>
#include <hip/hip_cooperative_groups.h>

namespace cg = cooperative_groups;

#define NN 50000
#define NE 600000
#define D  128
#define NBLK 196    // ceil(NN/256)
#define CGRID 784   // cooperative grid (<= co-resident capacity; 784*256 = 200704 threads)

typedef __attribute__((ext_vector_type(8))) short bf16x8;
typedef __attribute__((ext_vector_type(4))) float floatx4;

__device__ __forceinline__ unsigned short bf16_rne(float f) {
    union { float f; unsigned u; } v; v.f = f;
    unsigned r = v.u + 0x7FFFu + ((v.u >> 16) & 1u);
    return (unsigned short)(r >> 16);
}
__device__ __forceinline__ unsigned pack2(float a, float b) {
    return (unsigned)bf16_rne(a) | ((unsigned)bf16_rne(b) << 16);
}

// ---------------- fused CSR build (cooperative, replaces 6 dispatches) -------
// P1: deg=0, Wb=bf16(0.5*diag0*W), dummy rows=0
// P2: hist (deg via atomics)
// P3: per-block scan of deg -> row_ptr (pre-offset) + partials + dinv/rdeg
// P4: replicated 196-entry prefix of partials -> final row_ptr; fillc=0
// P5: CSR fill
__global__ __launch_bounds__(256) void build_kernel(const int* __restrict__ src,
                                                    const int* __restrict__ dst,
                                                    const float* __restrict__ W,
                                                    const float* __restrict__ diag,
                                                    unsigned short* __restrict__ Wb,
                                                    int* __restrict__ deg_i,
                                                    int* __restrict__ row_ptr,
                                                    int* __restrict__ fillc,
                                                    int* __restrict__ partials,
                                                    float* __restrict__ dinvf,
                                                    float* __restrict__ rdegf,
                                                    int* __restrict__ csr,
                                                    unsigned int* __restrict__ zrow0,
                                                    unsigned int* __restrict__ zrow1) {
    cg::grid_group grid = cg::this_grid();
    __shared__ int sh[256];
    const int t = threadIdx.x;
    const int b = blockIdx.x;
    const int g = b * 256 + t;
    const int G = CGRID * 256;

    // ---- P1 ----
    if (g < NN) deg_i[g] = 0;
    if (g < 16384) {
        int j = g & 127;
        Wb[g] = bf16_rne(0.5f * diag[j] * W[g]);
    }
    if (g < 64) { zrow0[g] = 0u; zrow1[g] = 0u; }
    grid.sync();

    // ---- P2: histogram ----
    for (int e = g; e < NE; e += G) atomicAdd(&deg_i[dst[e]], 1);
    grid.sync();

    // ---- P3: per-block inclusive scan ----
    if (b < NBLK) {
        int i = b * 256 + t;
        int dg = (i < NN) ? deg_i[i] : 0;
        if (i < NN) {
            float d = (float)dg;
            float dc = d > 1.0f ? d : 1.0f;       // clip(deg,1)
            dinvf[i] = rsqrtf(dc);
            rdegf[i] = sqrtf(dc);
        }
        sh[t] = dg;
        __syncthreads();
        #pragma unroll
        for (int off = 1; off < 256; off <<= 1) {
            int v = (t >= off) ? sh[t - off] : 0;
            __syncthreads();
            sh[t] += v;
            __syncthreads();
        }
        if (i < NN) row_ptr[i + 1] = sh[t];
        if (t == 255) partials[b] = sh[255];
    }
    grid.sync();

    // ---- P4: replicated prefix of partials + apply + fillc=0 ----
    if (b < NBLK) {
        sh[t] = (t < NBLK) ? partials[t] : 0;
        __syncthreads();
        #pragma unroll
        for (int off = 1; off < 256; off <<= 1) {
            int v = (t >= off) ? sh[t - off] : 0;
            __syncthreads();
            sh[t] += v;
            __syncthreads();
        }
        int add = (b > 0) ? sh[b - 1] : 0;
        int i = b * 256 + t;
        if (i < NN) {
            row_ptr[i + 1] += add;
            fillc[i] = 0;
        }
        if (g == 0) row_ptr[0] = 0;
    }
    grid.sync();

    // ---- P5: CSR fill ----
    for (int e = g; e < NE; e += G) {
        int tt = dst[e];
        int pos = row_ptr[tt] + atomicAdd(&fillc[tt], 1);
        csr[pos] = src[e];
    }
}

// ------------------------------- MFMA GEMM (h0) + featb_s byproduct
// out[i,d] = sum_j feat[i,j]*Wb[d,j] + b[d]        (fresh write)
// featb_s[i,:] = bf16(feat[i,:] * dinv[i])         (pre-scaled rows)
__global__ __launch_bounds__(256) void gemm_mfma_kernel(const float* __restrict__ feat,
                                                        const unsigned short* __restrict__ Wb,
                                                        const float* __restrict__ b,
                                                        const float* __restrict__ dinvf,
                                                        unsigned short* __restrict__ featb_s,
                                                        float* __restrict__ out) {
    const int wv   = threadIdx.x >> 6;
    const int lane = threadIdx.x & 63;
    const int r16  = lane & 15;
    const int quad = lane >> 4;
    const int m0   = blockIdx.x * 64 + wv * 16;

    const int mrow = m0 + r16;
    const int mc   = (mrow < NN) ? mrow : (NN - 1);
    const float* arow = feat + (size_t)mc * D + quad * 8;
    const float di = dinvf[mc];

    bf16x8 afrag[4];
    #pragma unroll
    for (int kc = 0; kc < 4; ++kc) {
        const float4 f0 = *(const float4*)(arow + kc * 32);
        const float4 f1 = *(const float4*)(arow + kc * 32 + 4);
        bf16x8 a;
        a[0] = (short)bf16_rne(f0.x); a[1] = (short)bf16_rne(f0.y);
        a[2] = (short)bf16_rne(f0.z); a[3] = (short)bf16_rne(f0.w);
        a[4] = (short)bf16_rne(f1.x); a[5] = (short)bf16_rne(f1.y);
        a[6] = (short)bf16_rne(f1.z); a[7] = (short)bf16_rne(f1.w);
        afrag[kc] = a;
        if (mrow < NN) {
            uint4 st;
            st.x = pack2(f0.x * di, f0.y * di);
            st.y = pack2(f0.z * di, f0.w * di);
            st.z = pack2(f1.x * di, f1.y * di);
            st.w = pack2(f1.z * di, f1.w * di);
            *(uint4*)(featb_s + (size_t)mc * D + quad * 8 + kc * 32) = st;
        }
    }

    floatx4 acc[8];
    #pragma unroll
    for (int nt = 0; nt < 8; ++nt) acc[nt] = (floatx4)(0.0f);

    #pragma unroll
    for (int nt = 0; nt < 8; ++nt) {
        const unsigned short* brow = Wb + (size_t)(nt * 16 + r16) * D + quad * 8;
        #pragma unroll
        for (int kc = 0; kc < 4; ++kc) {
            const bf16x8 bfrag = *(const bf16x8*)(brow + kc * 32);
            acc[nt] = __builtin_amdgcn_mfma_f32_16x16x32_bf16(afrag[kc], bfrag, acc[nt], 0, 0, 0);
        }
    }

    // C/D layout: col=lane&15 (d), row=quad*4+reg (i)
    #pragma unroll
    for (int nt = 0; nt < 8; ++nt) {
        const int d = nt * 16 + r16;
        const float bd = b[d];
        #pragma unroll
        for (int r = 0; r < 4; ++r) {
            const int i = m0 + quad * 4 + r;
            if (i < NN) out[(size_t)i * D + d] = acc[nt][r] + bd;
        }
    }
}

// --------------------------------------------- shared gather inner loop (R8)
// acc[2l..2l+1] = sum_e rows[csr[e], 2l..2l+1]   (rows pre-scaled by dinv[src])
// 8x unroll; padded slots point at zero row NN.
__device__ __forceinline__ float2 gather_acc(const unsigned short* __restrict__ rows,
                                             const int* __restrict__ csr,
                                             int e0, int e1, int lane) {
    float2 acc = make_float2(0.0f, 0.0f);
    for (int bse = e0; bse < e1; bse += 64) {
        int idx = bse + lane;
        int s = (idx < e1) ? csr[idx] : NN;          // NN = zero dummy row
        int cnt8 = (min(64, e1 - bse) + 7) & ~7;
        for (int k = 0; k < cnt8; k += 8) {
            #pragma unroll
            for (int u = 0; u < 8; ++u) {            // 8 independent load chains
                int ss = __shfl(s, k + u);
                unsigned pv = *(const unsigned*)(rows + (size_t)ss * D + 2 * lane);
                acc.x += __uint_as_float(pv << 16);
                acc.y += __uint_as_float(pv & 0xFFFF0000u);
            }
        }
    }
    return acc;
}

// round 1: feat1s = bf16( (feat0 - acc*dinv_i*diag1) * dinv_i )
__global__ __launch_bounds__(256) void gather1_kernel(const unsigned short* __restrict__ featb_s,
                                                      const int* __restrict__ csr,
                                                      const int* __restrict__ row_ptr,
                                                      const float* __restrict__ dinvf,
                                                      const float* __restrict__ diag,
                                                      const float* __restrict__ feat0,
                                                      unsigned int* __restrict__ feat1s) {
    const int node = blockIdx.x * 4 + (threadIdx.x >> 6);
    const int lane = threadIdx.x & 63;
    float2 acc = gather_acc(featb_s, csr, row_ptr[node], row_ptr[node + 1], lane);

    const size_t o2 = (size_t)node * (D / 2) + lane;
    const float di = dinvf[node];
    const float2 bs = *(const float2*)&feat0[2 * o2];
    const float2 dg = *(const float2*)&diag[D + 2 * lane];
    float rx = bs.x - acc.x * di * dg.x;
    float ry = bs.y - acc.y * di * dg.y;
    feat1s[o2] = pack2(rx * di, ry * di);
}

// round 2: out += -0.5*(feat1 + acc*dinv_i*diag2),  feat1 = feat1s*rdeg_i
__global__ __launch_bounds__(256) void gather2_kernel(const unsigned short* __restrict__ feat1s,
                                                      const int* __restrict__ csr,
                                                      const int* __restrict__ row_ptr,
                                                      const float* __restrict__ dinvf,
                                                      const float* __restrict__ rdegf,
                                                      const float* __restrict__ diag,
                                                      float* __restrict__ outp) {
    const int node = blockIdx.x * 4 + (threadIdx.x >> 6);
    const int lane = threadIdx.x & 63;
    float2 acc = gather_acc(feat1s, csr, row_ptr[node], row_ptr[node + 1], lane);

    const size_t o2 = (size_t)node * (D / 2) + lane;
    const float di = dinvf[node];
    const float rd = rdegf[node];
    const unsigned bp = ((const unsigned*)feat1s)[o2];
    const float2 dg = *(const float2*)&diag[2 * D + 2 * lane];
    float bx = __uint_as_float(bp << 16) * rd;          // unscale
    float by = __uint_as_float(bp & 0xFFFF0000u) * rd;
    float2 cur = *(const float2*)&outp[2 * o2];
    cur.x -= 0.5f * (bx + acc.x * di * dg.x);
    cur.y -= 0.5f * (by + acc.y * di * dg.y);
    *(float2*)&outp[2 * o2] = cur;
}

// ----------------------------------------------------------------- launch
extern "C" void kernel_launch(void* const* d_in, const int* in_sizes, int n_in,
                              void* d_out, int out_size, void* d_ws, size_t ws_size,
                              hipStream_t stream) {
    const float* feat = (const float*)d_in[0];
    const int*   eidx = (const int*)d_in[1];
    const float* diag = (const float*)d_in[2];
    const float* W    = (const float*)d_in[3];
    const float* b    = (const float*)d_in[4];
    float* out = (float*)d_out;

    const int* src = eidx;            // edge_index[0]
    const int* dst = eidx + NE;       // edge_index[1]

    // ---- workspace layout (~28.3 MB) ----
    unsigned short* featb_s = (unsigned short*)d_ws;             // (NN+1)*D bf16
    unsigned short* feat1s  = featb_s + (size_t)(NN + 1) * D;    // (NN+1)*D bf16
    int*   csr      = (int*)(feat1s + (size_t)(NN + 1) * D);     // NE ints
    float* dinvf    = (float*)(csr + NE);                        // NN
    float* rdegf    = dinvf + NN;                                // NN
    int*   deg_i    = (int*)(rdegf + NN);                        // NN
    int*   row_ptr  = deg_i + NN;                                // NN+2
    int*   fillc    = row_ptr + NN + 2;                          // NN
    int*   partials = fillc + NN;                                // 256
    unsigned short* Wb = (unsigned short*)(partials + 256);      // 32 KB

    unsigned int* zrow0 = (unsigned int*)(featb_s + (size_t)NN * D);
    unsigned int* zrow1 = (unsigned int*)(feat1s + (size_t)NN * D);

    // fused CSR build: prep + hist + scan1/2/3 + fill in ONE cooperative launch
    {
        void* args[] = {
            (void*)&src, (void*)&dst, (void*)&W, (void*)&diag,
            (void*)&Wb, (void*)&deg_i, (void*)&row_ptr, (void*)&fillc,
            (void*)&partials, (void*)&dinvf, (void*)&rdegf, (void*)&csr,
            (void*)&zrow0, (void*)&zrow1
        };
        hipLaunchCooperativeKernel((void*)build_kernel, dim3(CGRID), dim3(256),
                                   args, 0, stream);
    }

    // out = h0 + b; featb_s = bf16(feat*dinv) byproduct
    gemm_mfma_kernel<<<(NN + 63) / 64, 256, 0, stream>>>(feat, Wb, b, dinvf, featb_s, out);

    // round 1: feat1s = bf16(feat1 * dinv)
    gather1_kernel<<<NN / 4, 256, 0, stream>>>(featb_s, csr, row_ptr, dinvf, diag,
                                               feat, (unsigned int*)feat1s);
    // round 2: out += -0.5*(feat1 + agg2*dinv*diag2)
    gather2_kernel<<<NN / 4, 256, 0, stream>>>(feat1s, csr, row_ptr, dinvf, rdegf, diag, out);
}

// Round 11
// 223.419 us; speedup vs baseline: 2.3620x; 2.3620x over previous
//
#include <hip/hip_runtime.h>

#define NN 50000
#define NE 600000
#define D  128
#define NBLK 196   // ceil(NN/256)

typedef __attribute__((ext_vector_type(8))) short bf16x8;
typedef __attribute__((ext_vector_type(4))) float floatx4;

__device__ __forceinline__ unsigned short bf16_rne(float f) {
    union { float f; unsigned u; } v; v.f = f;
    unsigned r = v.u + 0x7FFFu + ((v.u >> 16) & 1u);
    return (unsigned short)(r >> 16);
}
__device__ __forceinline__ unsigned pack2(float a, float b) {
    return (unsigned)bf16_rne(a) | ((unsigned)bf16_rne(b) << 16);
}

// ---------- prep: deg=0, dummy rows=0, Wb = bf16(0.5*diag0*W) ----------
__global__ __launch_bounds__(256) void prep_kernel(const float* __restrict__ W,
                                                   const float* __restrict__ diag,
                                                   unsigned short* __restrict__ Wb,
                                                   int* __restrict__ deg_i,
                                                   unsigned int* __restrict__ zrow0,
                                                   unsigned int* __restrict__ zrow1) {
    int g = blockIdx.x * 256 + threadIdx.x;
    if (g < NN) deg_i[g] = 0;
    if (g < 16384) {
        int j = g & 127;
        Wb[g] = bf16_rne(0.5f * diag[j] * W[g]);
    }
    if (g < 64) { zrow0[g] = 0u; zrow1[g] = 0u; }
}

// ------------------------------------------------------------ histogram
__global__ __launch_bounds__(256) void hist_kernel(const int* __restrict__ dst,
                                                   int* __restrict__ deg_i) {
    int e = blockIdx.x * 256 + threadIdx.x;
    if (e < NE) atomicAdd(&deg_i[dst[e]], 1);
}

// ----------------------------------- scan1 (+ dinv & rdeg folded in)
__global__ __launch_bounds__(256) void scan1_kernel(const int* __restrict__ deg_i,
                                                    int* __restrict__ row_ptr,
                                                    int* __restrict__ partials,
                                                    float* __restrict__ dinvf,
                                                    float* __restrict__ rdegf) {
    __shared__ int sh[256];
    int i = blockIdx.x * 256 + threadIdx.x;
    int dg = (i < NN) ? deg_i[i] : 0;
    if (i < NN) {
        float d = (float)dg;
        float dc = d > 1.0f ? d : 1.0f;       // clip(deg,1)
        dinvf[i] = rsqrtf(dc);
        rdegf[i] = sqrtf(dc);                 // 1/dinv (for unscaling)
    }
    sh[threadIdx.x] = dg;
    __syncthreads();
    #pragma unroll
    for (int off = 1; off < 256; off <<= 1) {
        int t = (threadIdx.x >= off) ? sh[threadIdx.x - off] : 0;
        __syncthreads();
        sh[threadIdx.x] += t;
        __syncthreads();
    }
    if (i < NN) row_ptr[i + 1] = sh[threadIdx.x];
    if (threadIdx.x == 255) partials[blockIdx.x] = sh[255];
}

// ---------- scan23: replicated prefix of partials + apply + fillc=0 ----------
// Every block redundantly scans the 196-entry partials array (L2-hit reads,
// no cross-block sync needed) and applies its own offset. Merges the old
// single-block scan2 + scan3 dispatches into one.
__global__ __launch_bounds__(256) void scan23_kernel(int* __restrict__ row_ptr,
                                                     const int* __restrict__ partials,
                                                     int* __restrict__ fillc) {
    __shared__ int sh[256];
    const int t = threadIdx.x;
    sh[t] = (t < NBLK) ? partials[t] : 0;
    __syncthreads();
    #pragma unroll
    for (int off = 1; off < 256; off <<= 1) {
        int v = (t >= off) ? sh[t - off] : 0;
        __syncthreads();
        sh[t] += v;
        __syncthreads();
    }
    const int add = (blockIdx.x > 0) ? sh[blockIdx.x - 1] : 0;
    const int i = blockIdx.x * 256 + t;
    if (i < NN) {
        row_ptr[i + 1] += add;
        fillc[i] = 0;
    }
    if (i == 0) row_ptr[0] = 0;
}

// ------------------------------------------------------- CSR fill (int-only)
__global__ __launch_bounds__(256) void fill_kernel(const int* __restrict__ src,
                                                   const int* __restrict__ dst,
                                                   const int* __restrict__ row_ptr,
                                                   int* __restrict__ fillc,
                                                   int* __restrict__ csr) {
    int e = blockIdx.x * 256 + threadIdx.x;
    if (e < NE) {
        int t = dst[e];
        int pos = row_ptr[t] + atomicAdd(&fillc[t], 1);
        csr[pos] = src[e];
    }
}

// ------------------------------- MFMA GEMM (h0) + featb_s byproduct
// out[i,d] = sum_j feat[i,j]*Wb[d,j] + b[d]        (fresh write)
// featb_s[i,:] = bf16(feat[i,:] * dinv[i])         (pre-scaled rows)
__global__ __launch_bounds__(256) void gemm_mfma_kernel(const float* __restrict__ feat,
                                                        const unsigned short* __restrict__ Wb,
                                                        const float* __restrict__ b,
                                                        const float* __restrict__ dinvf,
                                                        unsigned short* __restrict__ featb_s,
                                                        float* __restrict__ out) {
    const int wv   = threadIdx.x >> 6;
    const int lane = threadIdx.x & 63;
    const int r16  = lane & 15;
    const int quad = lane >> 4;
    const int m0   = blockIdx.x * 64 + wv * 16;

    const int mrow = m0 + r16;
    const int mc   = (mrow < NN) ? mrow : (NN - 1);
    const float* arow = feat + (size_t)mc * D + quad * 8;
    const float di = dinvf[mc];

    bf16x8 afrag[4];
    #pragma unroll
    for (int kc = 0; kc < 4; ++kc) {
        const float4 f0 = *(const float4*)(arow + kc * 32);
        const float4 f1 = *(const float4*)(arow + kc * 32 + 4);
        bf16x8 a;
        a[0] = (short)bf16_rne(f0.x); a[1] = (short)bf16_rne(f0.y);
        a[2] = (short)bf16_rne(f0.z); a[3] = (short)bf16_rne(f0.w);
        a[4] = (short)bf16_rne(f1.x); a[5] = (short)bf16_rne(f1.y);
        a[6] = (short)bf16_rne(f1.z); a[7] = (short)bf16_rne(f1.w);
        afrag[kc] = a;
        if (mrow < NN) {
            uint4 st;
            st.x = pack2(f0.x * di, f0.y * di);
            st.y = pack2(f0.z * di, f0.w * di);
            st.z = pack2(f1.x * di, f1.y * di);
            st.w = pack2(f1.z * di, f1.w * di);
            *(uint4*)(featb_s + (size_t)mc * D + quad * 8 + kc * 32) = st;
        }
    }

    floatx4 acc[8];
    #pragma unroll
    for (int nt = 0; nt < 8; ++nt) acc[nt] = (floatx4)(0.0f);

    #pragma unroll
    for (int nt = 0; nt < 8; ++nt) {
        const unsigned short* brow = Wb + (size_t)(nt * 16 + r16) * D + quad * 8;
        #pragma unroll
        for (int kc = 0; kc < 4; ++kc) {
            const bf16x8 bfrag = *(const bf16x8*)(brow + kc * 32);
            acc[nt] = __builtin_amdgcn_mfma_f32_16x16x32_bf16(afrag[kc], bfrag, acc[nt], 0, 0, 0);
        }
    }

    // C/D layout: col=lane&15 (d), row=quad*4+reg (i)
    #pragma unroll
    for (int nt = 0; nt < 8; ++nt) {
        const int d = nt * 16 + r16;
        const float bd = b[d];
        #pragma unroll
        for (int r = 0; r < 4; ++r) {
            const int i = m0 + quad * 4 + r;
            if (i < NN) out[(size_t)i * D + d] = acc[nt][r] + bd;
        }
    }
}

// --------------------------------------------- shared gather inner loop
// acc[2l..2l+1] = sum_e rows[csr[e], 2l..2l+1]   (rows pre-scaled by dinv[src])
// 8x unroll; padded slots point at zero row NN.
__device__ __forceinline__ float2 gather_acc(const unsigned short* __restrict__ rows,
                                             const int* __restrict__ csr,
                                             int e0, int e1, int lane) {
    float2 acc = make_float2(0.0f, 0.0f);
    for (int bse = e0; bse < e1; bse += 64) {
        int idx = bse + lane;
        int s = (idx < e1) ? csr[idx] : NN;          // NN = zero dummy row
        int cnt8 = (min(64, e1 - bse) + 7) & ~7;
        for (int k = 0; k < cnt8; k += 8) {
            #pragma unroll
            for (int u = 0; u < 8; ++u) {            // 8 independent load chains
                int ss = __shfl(s, k + u);
                unsigned pv = *(const unsigned*)(rows + (size_t)ss * D + 2 * lane);
                acc.x += __uint_as_float(pv << 16);
                acc.y += __uint_as_float(pv & 0xFFFF0000u);
            }
        }
    }
    return acc;
}

// round 1: feat1s = bf16( (feat0 - acc*dinv_i*diag1) * dinv_i )
__global__ __launch_bounds__(256) void gather1_kernel(const unsigned short* __restrict__ featb_s,
                                                      const int* __restrict__ csr,
                                                      const int* __restrict__ row_ptr,
                                                      const float* __restrict__ dinvf,
                                                      const float* __restrict__ diag,
                                                      const float* __restrict__ feat0,
                                                      unsigned int* __restrict__ feat1s) {
    const int node = blockIdx.x * 4 + (threadIdx.x >> 6);
    const int lane = threadIdx.x & 63;
    float2 acc = gather_acc(featb_s, csr, row_ptr[node], row_ptr[node + 1], lane);

    const size_t o2 = (size_t)node * (D / 2) + lane;
    const float di = dinvf[node];
    const float2 bs = *(const float2*)&feat0[2 * o2];
    const float2 dg = *(const float2*)&diag[D + 2 * lane];
    float rx = bs.x - acc.x * di * dg.x;
    float ry = bs.y - acc.y * di * dg.y;
    feat1s[o2] = pack2(rx * di, ry * di);
}

// round 2: out += -0.5*(feat1 + acc*dinv_i*diag2),  feat1 = feat1s*rdeg_i
__global__ __launch_bounds__(256) void gather2_kernel(const unsigned short* __restrict__ feat1s,
                                                      const int* __restrict__ csr,
                                                      const int* __restrict__ row_ptr,
                                                      const float* __restrict__ dinvf,
                                                      const float* __restrict__ rdegf,
                                                      const float* __restrict__ diag,
                                                      float* __restrict__ outp) {
    const int node = blockIdx.x * 4 + (threadIdx.x >> 6);
    const int lane = threadIdx.x & 63;
    float2 acc = gather_acc(feat1s, csr, row_ptr[node], row_ptr[node + 1], lane);

    const size_t o2 = (size_t)node * (D / 2) + lane;
    const float di = dinvf[node];
    const float rd = rdegf[node];
    const unsigned bp = ((const unsigned*)feat1s)[o2];
    const float2 dg = *(const float2*)&diag[2 * D + 2 * lane];
    float bx = __uint_as_float(bp << 16) * rd;          // unscale
    float by = __uint_as_float(bp & 0xFFFF0000u) * rd;
    float2 cur = *(const float2*)&outp[2 * o2];
    cur.x -= 0.5f * (bx + acc.x * di * dg.x);
    cur.y -= 0.5f * (by + acc.y * di * dg.y);
    *(float2*)&outp[2 * o2] = cur;
}

// ----------------------------------------------------------------- launch
extern "C" void kernel_launch(void* const* d_in, const int* in_sizes, int n_in,
                              void* d_out, int out_size, void* d_ws, size_t ws_size,
                              hipStream_t stream) {
    const float* feat = (const float*)d_in[0];
    const int*   eidx = (const int*)d_in[1];
    const float* diag = (const float*)d_in[2];
    const float* W    = (const float*)d_in[3];
    const float* b    = (const float*)d_in[4];
    float* out = (float*)d_out;

    const int* src = eidx;            // edge_index[0]
    const int* dst = eidx + NE;       // edge_index[1]

    // ---- workspace layout (~28.3 MB) ----
    unsigned short* featb_s = (unsigned short*)d_ws;             // (NN+1)*D bf16
    unsigned short* feat1s  = featb_s + (size_t)(NN + 1) * D;    // (NN+1)*D bf16
    int*   csr      = (int*)(feat1s + (size_t)(NN + 1) * D);     // NE ints
    float* dinvf    = (float*)(csr + NE);                        // NN
    float* rdegf    = dinvf + NN;                                // NN
    int*   deg_i    = (int*)(rdegf + NN);                        // NN
    int*   row_ptr  = deg_i + NN;                                // NN+2
    int*   fillc    = row_ptr + NN + 2;                          // NN
    int*   partials = fillc + NN;                                // 256
    unsigned short* Wb = (unsigned short*)(partials + 256);      // 32 KB

    // prep: deg=0, dummy rows=0, Wb
    prep_kernel<<<NBLK, 256, 0, stream>>>(W, diag, Wb, deg_i,
                                          (unsigned int*)(featb_s + (size_t)NN * D),
                                          (unsigned int*)(feat1s + (size_t)NN * D));

    hist_kernel<<<(NE + 255) / 256, 256, 0, stream>>>(dst, deg_i);
    scan1_kernel<<<NBLK, 256, 0, stream>>>(deg_i, row_ptr, partials, dinvf, rdegf);
    scan23_kernel<<<NBLK, 256, 0, stream>>>(row_ptr, partials, fillc);
    fill_kernel<<<(NE + 255) / 256, 256, 0, stream>>>(src, dst, row_ptr, fillc, csr);

    // out = h0 + b; featb_s = bf16(feat*dinv) byproduct
    gemm_mfma_kernel<<<(NN + 63) / 64, 256, 0, stream>>>(feat, Wb, b, dinvf, featb_s, out);

    // round 1: feat1s = bf16(feat1 * dinv)
    gather1_kernel<<<NN / 4, 256, 0, stream>>>(featb_s, csr, row_ptr, dinvf, diag,
                                               feat, (unsigned int*)feat1s);
    // round 2: out += -0.5*(feat1 + agg2*dinv*diag2)
    gather2_kernel<<<NN / 4, 256, 0, stream>>>(feat1s, csr, row_ptr, dinvf, rdegf, diag, out);
}